// Round 10
// baseline (169.079 us; speedup 1.0000x reference)
//
#include <hip/hip_runtime.h>
#include <cstdint>
#include <cstddef>

typedef short s16x8 __attribute__((ext_vector_type(8)));
typedef float f32x16 __attribute__((ext_vector_type(16)));

#define WS_S     0
#define WS_ZERO  16384
#define WS_XQ    32768
#define XQ_BYTES (8 * 64 * 64 * 64 * 16)          // 33554432
#define WS_WQ    (WS_XQ + XQ_BYTES)               // 33587200
#define WQ_BYTES (4 * 32 * 9 * 2 * 128 * 8 * 2)   // 4718592
#define WS_NEEDED ((size_t)WS_WQ + (size_t)WQ_BYTES)

__device__ __forceinline__ short f2bf(float f) {
  unsigned u = __builtin_bit_cast(unsigned, f);
  unsigned r = (u + 0x7fffu + ((u >> 16) & 1u)) >> 16;  // RNE
  return (short)r;
}

__device__ __forceinline__ void gload_lds16(const void* g, void* l) {
  __builtin_amdgcn_global_load_lds(
      (const __attribute__((address_space(1))) void*)g,
      (__attribute__((address_space(3))) void*)l, 16, 0, 0);
}

// ---- s = style @ mod_w^T + mod_b ; one wave per (b,c). Also zeroes zerobuf.
__global__ void k_style(const float* __restrict__ style,
                        const float* __restrict__ mod_w,
                        const float* __restrict__ mod_b,
                        float* __restrict__ s_out,
                        float* __restrict__ zb) {
  if (blockIdx.x == 0) zb[threadIdx.x] = 0.0f;  // 256 floats = 1 KB zero page
  int wave = threadIdx.x >> 6, lane = threadIdx.x & 63;
  int wid = blockIdx.x * 4 + wave;   // 0..4095
  int b = wid >> 9, c = wid & 511;
  const float4* st = (const float4*)(style + b * 512);
  const float4* mw = (const float4*)(mod_w + c * 512);
  float4 a0 = st[lane * 2], a1 = st[lane * 2 + 1];
  float4 b0 = mw[lane * 2], b1 = mw[lane * 2 + 1];
  float sum = a0.x * b0.x + a0.y * b0.y + a0.z * b0.z + a0.w * b0.w +
              a1.x * b1.x + a1.y * b1.y + a1.z * b1.z + a1.w * b1.w;
  #pragma unroll
  for (int off = 32; off; off >>= 1) sum += __shfl_down(sum, off);
  if (lane == 0) s_out[b * 512 + c] = sum + mod_b[c];
}

// ---- xq[b][h][cgrp][w][8] = bf16(x[b][cgrp*8+j][h][w] * s[b][cgrp*8+j])
__global__ void k_xq(const float* __restrict__ x, const float* __restrict__ s,
                     char* __restrict__ xq) {
  int t = blockIdx.x * 256 + threadIdx.x;        // 2,097,152 total
  int w = t & 63, cg = (t >> 6) & 63, h = (t >> 12) & 63, b = t >> 18;
  const float* xp = x + (((b * 512 + cg * 8) * 64 + h) * 64 + w);
  const float* sp = s + b * 512 + cg * 8;
  s16x8 v;
  #pragma unroll
  for (int j = 0; j < 8; ++j) v[j] = f2bf(xp[j * 4096] * sp[j]);
  *(s16x8*)(xq + (size_t)t * 16) = v;
}

// ---- wq[nb][chunk][tap][kg][n][8k] = bf16(weight[nb*128+n][chunk*16+kg*8+k][tap])
__global__ void k_wq(const float* __restrict__ wt, char* __restrict__ wq) {
  int tap = blockIdx.x, ch = blockIdx.y, nb = blockIdx.z;
  int kg = threadIdx.x >> 7, n = threadIdx.x & 127;
  const float* wp = wt + ((size_t)(nb * 128 + n) * 512 + ch * 16 + kg * 8) * 9 + tap;
  s16x8 v;
  #pragma unroll
  for (int j = 0; j < 8; ++j) v[j] = f2bf(wp[j * 9]);
  size_t idx = ((size_t)(nb * 32 + ch) * 9 + tap) * 256 + kg * 128 + n;  // 16B units
  *(s16x8*)(wq + idx * 16) = v;
}

// ---- conv: block = 128 couts (nb) x 512 pixels (8 rows of one image)
// 8 waves (2 cout-halves x 4 pixel-slices), wave tile 64 couts x 128 px.
// Forced software pipeline: inline-asm ds_read_b128 (can't be sunk) + counted
// lgkmcnt + sched_barrier fences; two fragment sets S0/S1 alternate so reads
// for kw+1 complete underneath the MFMA cluster for kw. One s_barrier/chunk.
__global__ __launch_bounds__(512, 2) void k_conv(
    const char* __restrict__ xq, const char* __restrict__ wq,
    const char* __restrict__ zerob, float* __restrict__ out) {
  extern __shared__ char smem[];
  // layout: wt[2][36864] then xs[2][21120]   total 115968 B
  char* wt_base = smem;
  char* xs_base = smem + 73728;

  const int tid = threadIdx.x;
  const int lane = tid & 63, wave = tid >> 6;
  const int l5 = lane >> 5, l31 = lane & 31;
  const int wc = wave >> 2;            // cout half (0,1)
  const int wp = wave & 3;             // pixel slice (2 rows each)
  const int mb = blockIdx.x, nb = blockIdx.y;
  const int b = mb >> 3;               // 8 m-blocks (of 8 rows) per image
  const int row0 = (mb & 7) << 3;      // first of the 8 output rows

  // zero halo columns (col 0 and 65 of each [row j][kg] plane) in BOTH buffers
  if (tid < 80) {
    int dbuf = tid / 40, q = tid % 40;
    int j = q >> 2, kg = (q >> 1) & 1, side = q & 1;
    s16x8 z = {0, 0, 0, 0, 0, 0, 0, 0};
    *(s16x8*)(xs_base + dbuf * 21120 + ((j * 2 + kg) * 66 + side * 65) * 16) = z;
  }

  f32x16 acc[2][4];
  #pragma unroll
  for (int i = 0; i < 2; ++i)
    #pragma unroll
    for (int j = 0; j < 4; ++j)
      #pragma unroll
      for (int e = 0; e < 16; ++e) acc[i][j][e] = 0.0f;

  // staging source bases (per-lane)
  const char* wq_base = wq + (size_t)nb * (32 * 36864) + lane * 16;
  const char* xq_base = xq + (size_t)b * 4194304 + lane * 16;

  // per-lane LDS byte-offset bases (generic-ptr low 32 bits = LDS offset)
  const unsigned xs0 = (unsigned)(size_t)xs_base + wp * 4224 + l5 * 1056 + l31 * 16;
  const unsigned wt0 = (unsigned)(size_t)wt_base + wc * 1024 + l5 * 2048 + l31 * 16;

  // ---- stage chunk `ch` into buffer `buf`: 56 x 1KB segs, 7 per wave
  #define STAGE(buf, ch)                                                      \
    _Pragma("unroll")                                                         \
    for (int i = 0; i < 7; ++i) {                                             \
      int seg = wave * 7 + i;             /* 0..55, wave-uniform */           \
      if (seg < 36) {                                                         \
        gload_lds16(wq_base + (size_t)(ch) * 36864 + seg * 1024,              \
                    wt_base + (buf) * 36864 + seg * 1024);                    \
      } else {                                                                \
        int q = seg - 36, j = q >> 1, kg = q & 1;                             \
        int h = row0 - 1 + j;                                                 \
        const char* src = (h >= 0 && h < 64)                                  \
            ? xq_base + (size_t)(h * 64 + (ch) * 2 + kg) * 1024               \
            : zerob + lane * 16;                                              \
        gload_lds16(src, xs_base + (buf) * 21120 + ((j * 2 + kg) * 66 + 1) * 16); \
      }                                                                       \
    }

  #define DSR(d, base, o) \
    asm volatile("ds_read_b128 %0, %1 offset:" o : "=v"(d) : "v"(base))
  #define SB() __builtin_amdgcn_sched_barrier(0)

  // MFMA cluster for one kw, consuming fragment set (aS,bS)
  #define MCL(aS, bS)                                                        \
    __builtin_amdgcn_s_setprio(1);                                           \
    _Pragma("unroll") for (int kh = 0; kh < 3; ++kh)                         \
      _Pragma("unroll") for (int ct = 0; ct < 2; ++ct)                       \
        _Pragma("unroll") for (int pt = 0; pt < 4; ++pt)                     \
          acc[ct][pt] = __builtin_amdgcn_mfma_f32_32x32x16_bf16(             \
              aS[kh][ct], bS[(pt >> 1) + kh][pt & 1], acc[ct][pt], 0, 0, 0); \
    __builtin_amdgcn_s_setprio(0);

  STAGE(0, 0);
  asm volatile("s_waitcnt vmcnt(0) lgkmcnt(0)" ::: "memory");
  __builtin_amdgcn_s_barrier();

  s16x8 aS0[3][2], bS0[4][2], aS1[3][2], bS1[4][2];

  for (int ch = 0; ch < 32; ++ch) {
    const int cur = ch & 1;
    const unsigned bxs = xs0 + cur * 21120;
    const unsigned bwt = wt0 + cur * 36864;

    // R1: kw0 full set -> S0 (8 B + 6 A)
    DSR(bS0[0][0], bxs, "0");     DSR(bS0[0][1], bxs, "512");
    DSR(bS0[1][0], bxs, "2112");  DSR(bS0[1][1], bxs, "2624");
    DSR(bS0[2][0], bxs, "4224");  DSR(bS0[2][1], bxs, "4736");
    DSR(bS0[3][0], bxs, "6336");  DSR(bS0[3][1], bxs, "6848");
    DSR(aS0[0][0], bwt, "0");     DSR(aS0[0][1], bwt, "512");
    DSR(aS0[1][0], bwt, "12288"); DSR(aS0[1][1], bwt, "12800");
    DSR(aS0[2][0], bwt, "24576"); DSR(aS0[2][1], bwt, "25088");
    // R2: kw1 B -> S1
    DSR(bS1[0][0], bxs, "16");    DSR(bS1[0][1], bxs, "528");
    DSR(bS1[1][0], bxs, "2128");  DSR(bS1[1][1], bxs, "2640");
    DSR(bS1[2][0], bxs, "4240");  DSR(bS1[2][1], bxs, "4752");
    DSR(bS1[3][0], bxs, "6352");  DSR(bS1[3][1], bxs, "6864");

    if (ch < 31) STAGE(cur ^ 1, ch + 1);

    asm volatile("s_waitcnt lgkmcnt(8)" ::: "memory");  // S0 ready (R2 may fly)
    SB();
    MCL(aS0, bS0);   // kw = 0
    SB();

    // R3: kw1 A -> S1 ; R4: kw2 B -> S0 (overwrites consumed bS0)
    DSR(aS1[0][0], bwt, "4096");  DSR(aS1[0][1], bwt, "4608");
    DSR(aS1[1][0], bwt, "16384"); DSR(aS1[1][1], bwt, "16896");
    DSR(aS1[2][0], bwt, "28672"); DSR(aS1[2][1], bwt, "29184");
    DSR(bS0[0][0], bxs, "32");    DSR(bS0[0][1], bxs, "544");
    DSR(bS0[1][0], bxs, "2144");  DSR(bS0[1][1], bxs, "2656");
    DSR(bS0[2][0], bxs, "4256");  DSR(bS0[2][1], bxs, "4768");
    DSR(bS0[3][0], bxs, "6368");  DSR(bS0[3][1], bxs, "6880");

    asm volatile("s_waitcnt lgkmcnt(8)" ::: "memory");  // S1 ready (R4 may fly)
    SB();
    MCL(aS1, bS1);   // kw = 1
    SB();

    // R5: kw2 A -> S0
    DSR(aS0[0][0], bwt, "8192");  DSR(aS0[0][1], bwt, "8704");
    DSR(aS0[1][0], bwt, "20480"); DSR(aS0[1][1], bwt, "20992");
    DSR(aS0[2][0], bwt, "32768"); DSR(aS0[2][1], bwt, "33280");

    asm volatile("s_waitcnt lgkmcnt(0)" ::: "memory");  // all ready
    SB();
    MCL(aS0, bS0);   // kw = 2
    SB();

    asm volatile("s_waitcnt vmcnt(0)" ::: "memory");    // staging issued ~1 chunk ago
    __builtin_amdgcn_s_barrier();
  }

  // epilogue: D row = cout, col = pixel (lanes 0..31 contiguous w -> coalesced)
  #pragma unroll
  for (int ct = 0; ct < 2; ++ct) {
    #pragma unroll
    for (int pt = 0; pt < 4; ++pt) {
      int h = row0 + wp * 2 + (pt >> 1);
      int w = (pt & 1) * 32 + l31;
      int cb = nb * 128 + wc * 64 + ct * 32 + 4 * l5;
      #pragma unroll
      for (int rg = 0; rg < 16; ++rg) {
        int cout = cb + (rg & 3) + 8 * (rg >> 2);
        out[((size_t)(b * 512 + cout) * 4096) + h * 64 + w] = acc[ct][pt][rg];
      }
    }
  }
  #undef STAGE
  #undef DSR
  #undef SB
  #undef MCL
}

// ---- emergency fallback (tiny ws): fp32 direct conv, s recomputed per block
__global__ void k_naive(const float* __restrict__ x, const float* __restrict__ style,
                        const float* __restrict__ wt, const float* __restrict__ mw,
                        const float* __restrict__ mb_, float* __restrict__ out) {
  __shared__ float s_sh[512];
  int h = blockIdx.x, co = blockIdx.y, b = blockIdx.z, w = threadIdx.x;
  for (int c = w; c < 512; c += 64) {
    float a = mb_[c];
    for (int k = 0; k < 512; ++k) a += style[b * 512 + k] * mw[c * 512 + k];
    s_sh[c] = a;
  }
  __syncthreads();
  float acc = 0.0f;
  for (int c = 0; c < 512; ++c) {
    float sc = s_sh[c];
    const float* wp = wt + ((size_t)co * 512 + c) * 9;
    for (int kh = 0; kh < 3; ++kh) {
      int hy = h + kh - 1;
      if (hy < 0 || hy >= 64) continue;
      for (int kw = 0; kw < 3; ++kw) {
        int wx = w + kw - 1;
        if (wx < 0 || wx >= 64) continue;
        acc += wp[kh * 3 + kw] * x[((size_t)(b * 512 + c) * 64 + hy) * 64 + wx] * sc;
      }
    }
  }
  out[((size_t)(b * 512 + co) * 64 + h) * 64 + w] = acc;
}

extern "C" void kernel_launch(void* const* d_in, const int* in_sizes, int n_in,
                              void* d_out, int out_size, void* d_ws, size_t ws_size,
                              hipStream_t stream) {
  const float* x      = (const float*)d_in[0];
  const float* style  = (const float*)d_in[1];
  const float* weight = (const float*)d_in[2];
  const float* mod_w  = (const float*)d_in[3];
  const float* mod_b  = (const float*)d_in[4];
  float* out = (float*)d_out;
  char* ws = (char*)d_ws;

  if (ws_size >= WS_NEEDED) {
    float* s  = (float*)(ws + WS_S);
    float* zb = (float*)(ws + WS_ZERO);
    char* xq  = ws + WS_XQ;
    char* wq  = ws + WS_WQ;
    k_style<<<1024, 256, 0, stream>>>(style, mod_w, mod_b, s, zb);
    k_xq<<<8192, 256, 0, stream>>>(x, s, xq);
    k_wq<<<dim3(9, 32, 4), 256, 0, stream>>>(weight, wq);
    k_conv<<<dim3(64, 4), 512, 115968, stream>>>(xq, wq, (const char*)zb, out);
  } else {
    k_naive<<<dim3(64, 512, 8), 64, 0, stream>>>(x, style, weight, mod_w, mod_b, out);
  }
}

// Round 11
// 153.341 us; speedup vs baseline: 1.1026x; 1.1026x over previous
//
#include <hip/hip_runtime.h>
#include <cstdint>
#include <cstddef>

typedef short s16x8 __attribute__((ext_vector_type(8)));
typedef float f32x16 __attribute__((ext_vector_type(16)));

#define WS_S     0
#define WS_WQ    32768
#define WQ_BYTES (4 * 32 * 9 * 2 * 128 * 8 * 2)   // 4718592
#define WS_NEEDED ((size_t)WS_WQ + (size_t)WQ_BYTES)

__device__ __forceinline__ short f2bf(float f) {
  unsigned u = __builtin_bit_cast(unsigned, f);
  unsigned r = (u + 0x7fffu + ((u >> 16) & 1u)) >> 16;  // RNE
  return (short)r;
}

__device__ __forceinline__ void gload_lds16(const void* g, void* l) {
  __builtin_amdgcn_global_load_lds(
      (const __attribute__((address_space(1))) void*)g,
      (__attribute__((address_space(3))) void*)l, 16, 0, 0);
}

// ---- merged prep: blocks 0..1023 = style dot (s = style@mod_w^T + mod_b),
//                   blocks 1024..2175 = weight re-tile wq
__global__ void k_prep(const float* __restrict__ style,
                       const float* __restrict__ mod_w,
                       const float* __restrict__ mod_b,
                       const float* __restrict__ wt,
                       float* __restrict__ s_out,
                       char* __restrict__ wq) {
  int bid = blockIdx.x;
  if (bid < 1024) {
    int wave = threadIdx.x >> 6, lane = threadIdx.x & 63;
    int wid = bid * 4 + wave;   // 0..4095
    int b = wid >> 9, c = wid & 511;
    const float4* st = (const float4*)(style + b * 512);
    const float4* mw = (const float4*)(mod_w + c * 512);
    float4 a0 = st[lane * 2], a1 = st[lane * 2 + 1];
    float4 b0 = mw[lane * 2], b1 = mw[lane * 2 + 1];
    float sum = a0.x * b0.x + a0.y * b0.y + a0.z * b0.z + a0.w * b0.w +
                a1.x * b1.x + a1.y * b1.y + a1.z * b1.z + a1.w * b1.w;
    #pragma unroll
    for (int off = 32; off; off >>= 1) sum += __shfl_down(sum, off);
    if (lane == 0) s_out[b * 512 + c] = sum + mod_b[c];
  } else {
    int q = bid - 1024;               // 0..1151
    int tap = q % 9, t2 = q / 9;
    int ch = t2 % 32, nb = t2 / 32;
    int kg = threadIdx.x >> 7, n = threadIdx.x & 127;
    const float* wp = wt + ((size_t)(nb * 128 + n) * 512 + ch * 16 + kg * 8) * 9 + tap;
    s16x8 v;
    #pragma unroll
    for (int j = 0; j < 8; ++j) v[j] = f2bf(wp[j * 9]);
    size_t idx = ((size_t)(nb * 32 + ch) * 9 + tap) * 256 + kg * 128 + n;  // 16B units
    *(s16x8*)(wq + idx * 16) = v;
  }
}

// ---- conv: block = 128 couts (nb) x 512 pixels (8 rows of one image)
// 8 waves (2 cout-halves x 4 pixel-slices), wave tile 64 couts x 128 px.
// R3 compute structure EXACTLY (123 us proven). Fused modulation staging:
// x-tiles loaded fp32 from global (L3-resident) at chunk top (issue-early),
// scaled by s, cvt_pk to bf16, ds_write to next xs buffer at chunk end
// (write-late), same single __syncthreads per chunk. Weights via gload_lds.
__global__ __launch_bounds__(512, 2) void k_conv(
    const float* __restrict__ x, const float* __restrict__ sbuf,
    const char* __restrict__ wq, float* __restrict__ out) {
  extern __shared__ char smem[];
  // layout: wt[2][36864] then xs[2][21120]   total 115968 B
  char* wt_base = smem;
  char* xs_base = smem + 73728;

  const int tid = threadIdx.x;
  const int lane = tid & 63, wave = tid >> 6;
  const int l5 = lane >> 5, l31 = lane & 31;
  const int wc = wave >> 2;            // cout half (0,1)
  const int wp = wave & 3;             // pixel slice (2 rows each)
  const int mb = blockIdx.x, nb = blockIdx.y;
  const int b = mb >> 3;               // 8 m-blocks (of 8 rows) per image
  const int row0 = (mb & 7) << 3;      // first of the 8 output rows

  // zero halo columns (col 0 and 65 of each [row j][kg] plane) in BOTH buffers
  if (tid < 80) {
    int dbuf = tid / 40, q = tid % 40;
    int j = q >> 2, kg = (q >> 1) & 1, side = q & 1;
    s16x8 z = {0, 0, 0, 0, 0, 0, 0, 0};
    *(s16x8*)(xs_base + dbuf * 21120 + ((j * 2 + kg) * 66 + side * 65) * 16) = z;
  }

  f32x16 acc[2][4];
  #pragma unroll
  for (int i = 0; i < 2; ++i)
    #pragma unroll
    for (int j = 0; j < 4; ++j)
      #pragma unroll
      for (int e = 0; e < 16; ++e) acc[i][j][e] = 0.0f;

  const char* wq_base = wq + (size_t)nb * (32 * 36864) + lane * 16;
  const float* sv = sbuf + b * 512;

  const int a_off = l5 * 2048 + l31 * 16;       // within wt chunk (kg, n)
  const int b_off = l5 * 1056 + l31 * 16;       // within xs chunk (kg, col)
  const int xs_woff = wp * 4224;                // wave's 2-row pixel slice

  // ---- weight staging: 36 x 1KB segs, 5 per wave (wave7 does 1)
  #define STAGE_WT(buf, chv)                                                  \
    _Pragma("unroll")                                                         \
    for (int i = 0; i < 5; ++i) {                                             \
      int seg = wave * 5 + i;                                                 \
      if (seg < 36)                                                           \
        gload_lds16(wq_base + (size_t)(chv) * 36864 + seg * 1024,             \
                    wt_base + (buf) * 36864 + seg * 1024);                    \
    }

  // ---- x staging (fused modulation). 1280 slots = (10 rows)x(2 kg)x(64 col);
  // slot = tid + it*512 -> j=slot>>7, kg=(slot>>6)&1, col=slot&63 (wave-uniform j,kg)
  float xr[3][8]; float sr[3][8];
  #define XLOAD(chv)                                                          \
    _Pragma("unroll")                                                         \
    for (int it = 0; it < 3; ++it) {                                          \
      int slot = tid + it * 512;                                              \
      if (slot < 1280) {                                                      \
        int j = slot >> 7, kg = (slot >> 6) & 1, col = slot & 63;             \
        int h = row0 - 1 + j;                                                 \
        int c0 = (chv) * 16 + kg * 8;                                         \
        if (h >= 0 && h < 64) {                                               \
          const float* xp = x + ((size_t)(b * 512 + c0) << 12) + h * 64 + col;\
          _Pragma("unroll")                                                   \
          for (int jj = 0; jj < 8; ++jj) xr[it][jj] = xp[(size_t)jj << 12];   \
          *(float4*)&sr[it][0] = *(const float4*)(sv + c0);                   \
          *(float4*)&sr[it][4] = *(const float4*)(sv + c0 + 4);               \
        }                                                                     \
      }                                                                       \
    }

  #define CWRITE(buf)                                                         \
    _Pragma("unroll")                                                         \
    for (int it = 0; it < 3; ++it) {                                          \
      int slot = tid + it * 512;                                              \
      if (slot < 1280) {                                                      \
        int j = slot >> 7, kg = (slot >> 6) & 1, col = slot & 63;             \
        int h = row0 - 1 + j;                                                 \
        int4 iv = {0, 0, 0, 0};                                               \
        if (h >= 0 && h < 64) {                                               \
          unsigned pk0, pk1, pk2, pk3;                                        \
          asm("v_cvt_pk_bf16_f32 %0, %1, %2" : "=v"(pk0)                      \
              : "v"(xr[it][0] * sr[it][0]), "v"(xr[it][1] * sr[it][1]));      \
          asm("v_cvt_pk_bf16_f32 %0, %1, %2" : "=v"(pk1)                      \
              : "v"(xr[it][2] * sr[it][2]), "v"(xr[it][3] * sr[it][3]));      \
          asm("v_cvt_pk_bf16_f32 %0, %1, %2" : "=v"(pk2)                      \
              : "v"(xr[it][4] * sr[it][4]), "v"(xr[it][5] * sr[it][5]));      \
          asm("v_cvt_pk_bf16_f32 %0, %1, %2" : "=v"(pk3)                      \
              : "v"(xr[it][6] * sr[it][6]), "v"(xr[it][7] * sr[it][7]));      \
          iv.x = (int)pk0; iv.y = (int)pk1; iv.z = (int)pk2; iv.w = (int)pk3; \
        }                                                                     \
        *(int4*)(xs_base + (buf) * 21120 + ((j * 2 + kg) * 66 + 1 + col) * 16) = iv; \
      }                                                                       \
    }

  STAGE_WT(0, 0);
  XLOAD(0);
  CWRITE(0);          // compiler auto-waits vmcnt for xr deps
  __syncthreads();    // drains gload_lds + ds_writes + halo writes

  for (int ch = 0; ch < 32; ++ch) {
    const int cur = ch & 1;
    if (ch < 31) { STAGE_WT(cur ^ 1, ch + 1); XLOAD(ch + 1); }

    const char* wt = wt_base + cur * 36864;
    const char* xs_w = xs_base + cur * 21120 + xs_woff;

    #pragma unroll
    for (int kw = 0; kw < 3; ++kw) {
      // B-fragment cache: 4 input rows x 2 col-halves, reused across kh
      s16x8 bC[4][2];
      #pragma unroll
      for (int r4 = 0; r4 < 4; ++r4)
        #pragma unroll
        for (int chh = 0; chh < 2; ++chh)
          bC[r4][chh] = *(const s16x8*)(xs_w + (r4 * 132 + chh * 32 + kw) * 16 + b_off);
      #pragma unroll
      for (int kh = 0; kh < 3; ++kh) {
        const int tap = kh * 3 + kw;
        s16x8 afr[2];
        #pragma unroll
        for (int ct = 0; ct < 2; ++ct)
          afr[ct] = *(const s16x8*)(wt + tap * 4096 + (wc * 2 + ct) * 512 + a_off);
        __builtin_amdgcn_s_setprio(1);
        #pragma unroll
        for (int ct = 0; ct < 2; ++ct)
          #pragma unroll
          for (int pt = 0; pt < 4; ++pt)
            acc[ct][pt] = __builtin_amdgcn_mfma_f32_32x32x16_bf16(
                afr[ct], bC[(pt >> 1) + kh][pt & 1], acc[ct][pt], 0, 0, 0);
        __builtin_amdgcn_s_setprio(0);
      }
    }

    if (ch < 31) CWRITE(cur ^ 1);   // write NEXT buffer (not being read)
    __syncthreads();                // next wt+xs staged; reads of cur done
  }

  // epilogue: D row = cout, col = pixel (lanes 0..31 contiguous w -> coalesced)
  #pragma unroll
  for (int ct = 0; ct < 2; ++ct) {
    #pragma unroll
    for (int pt = 0; pt < 4; ++pt) {
      int h = row0 + wp * 2 + (pt >> 1);
      int w = (pt & 1) * 32 + l31;
      int cb = nb * 128 + wc * 64 + ct * 32 + 4 * l5;
      #pragma unroll
      for (int rg = 0; rg < 16; ++rg) {
        int cout = cb + (rg & 3) + 8 * (rg >> 2);
        out[((size_t)(b * 512 + cout) * 4096) + h * 64 + w] = acc[ct][pt][rg];
      }
    }
  }
  #undef STAGE_WT
  #undef XLOAD
  #undef CWRITE
}

// ---- emergency fallback (tiny ws): fp32 direct conv, s recomputed per block
__global__ void k_naive(const float* __restrict__ x, const float* __restrict__ style,
                        const float* __restrict__ wt, const float* __restrict__ mw,
                        const float* __restrict__ mb_, float* __restrict__ out) {
  __shared__ float s_sh[512];
  int h = blockIdx.x, co = blockIdx.y, b = blockIdx.z, w = threadIdx.x;
  for (int c = w; c < 512; c += 64) {
    float a = mb_[c];
    for (int k = 0; k < 512; ++k) a += style[b * 512 + k] * mw[c * 512 + k];
    s_sh[c] = a;
  }
  __syncthreads();
  float acc = 0.0f;
  for (int c = 0; c < 512; ++c) {
    float sc = s_sh[c];
    const float* wp = wt + ((size_t)co * 512 + c) * 9;
    for (int kh = 0; kh < 3; ++kh) {
      int hy = h + kh - 1;
      if (hy < 0 || hy >= 64) continue;
      for (int kw = 0; kw < 3; ++kw) {
        int wx = w + kw - 1;
        if (wx < 0 || wx >= 64) continue;
        acc += wp[kh * 3 + kw] * x[((size_t)(b * 512 + c) * 64 + hy) * 64 + wx] * sc;
      }
    }
  }
  out[((size_t)(b * 512 + co) * 64 + h) * 64 + w] = acc;
}

extern "C" void kernel_launch(void* const* d_in, const int* in_sizes, int n_in,
                              void* d_out, int out_size, void* d_ws, size_t ws_size,
                              hipStream_t stream) {
  const float* x      = (const float*)d_in[0];
  const float* style  = (const float*)d_in[1];
  const float* weight = (const float*)d_in[2];
  const float* mod_w  = (const float*)d_in[3];
  const float* mod_b  = (const float*)d_in[4];
  float* out = (float*)d_out;
  char* ws = (char*)d_ws;

  if (ws_size >= WS_NEEDED) {
    float* s  = (float*)(ws + WS_S);
    char* wq  = ws + WS_WQ;
    k_prep<<<2176, 256, 0, stream>>>(style, mod_w, mod_b, weight, s, wq);
    k_conv<<<dim3(64, 4), 512, 115968, stream>>>(x, s, wq, out);
  } else {
    k_naive<<<dim3(64, 512, 8), 64, 0, stream>>>(x, style, weight, mod_w, mod_b, out);
  }
}